// Round 3
// baseline (529.375 us; speedup 1.0000x reference)
//
#include <hip/hip_runtime.h>
#include <math.h>

constexpr int D  = 64;
constexpr int T  = 200;
constexpr int H0 = 80;
constexpr int H1 = 40;
constexpr int BLOCK = 256;
constexpr float NEG_INF_V = -4294967295.0f;

typedef float f8 __attribute__((ext_vector_type(8)));

__global__ __launch_bounds__(BLOCK) void attn_fused(
    const float* __restrict__ q, const float* __restrict__ k,
    const float* __restrict__ v, const float* __restrict__ W0,
    const float* __restrict__ b0, const float* __restrict__ a0,
    const float* __restrict__ W1, const float* __restrict__ b1,
    const float* __restrict__ a1, const float* __restrict__ Wo,
    const float* __restrict__ bo, const int* __restrict__ mask,
    float* __restrict__ out)
{
    __shared__ float s_q[D];
    __shared__ __align__(16) float s_weff[D][H0];   // 20 KB folded layer-1
    __shared__ __align__(16) float s_W1[H0][H1];    // 12.8 KB
    __shared__ __align__(16) float s_biasq[H0];
    __shared__ __align__(16) float s_a0[H0];
    __shared__ __align__(16) float s_b1[H1];
    __shared__ __align__(16) float s_a1[H1];
    __shared__ __align__(16) float s_Wo[H1];
    __shared__ float s_w[BLOCK];
    __shared__ float s_red[8];
    __shared__ float s_part[4][D];

    const int tid = threadIdx.x;
    const int b   = blockIdx.x;

    // ---- Phase A: stage weights, fold layer-1 per batch ----
    if (tid < D) s_q[tid] = q[(size_t)b * D + tid];
    for (int i = tid; i < H0 * H1; i += BLOCK) ((float*)s_W1)[i] = W1[i];
    if (tid < H1) { s_b1[tid] = b1[tid]; s_a1[tid] = a1[tid]; s_Wo[tid] = Wo[tid]; }
    if (tid < H0) s_a0[tid] = a0[tid];
    __syncthreads();

    for (int i = tid; i < D * H0; i += BLOCK) {
        int d = i / H0;
        ((float*)s_weff)[i] = W0[64 * H0 + i] - W0[128 * H0 + i]
                            + s_q[d] * W0[192 * H0 + i];
    }
    if (tid < H0) {
        float acc = b0[tid];
        #pragma unroll 4
        for (int d = 0; d < D; ++d)
            acc = fmaf(s_q[d], W0[d * H0 + tid] + W0[(128 + d) * H0 + tid], acc);
        s_biasq[tid] = acc;
    }
    __syncthreads();

    // ---- Phase B: thread t = tid computes the MLP logit ----
    float logit;
    if (tid < T) {
        const float4* kp4 = (const float4*)(k + ((size_t)b * T + tid) * D);
        float4 kr[16];
        #pragma unroll
        for (int i = 0; i < 16; ++i) kr[i] = kp4[i];

        float h1acc[H1];
        #pragma unroll
        for (int g = 0; g < H1; ++g) h1acc[g] = 0.0f;

        #pragma unroll 1
        for (int hbi = 0; hbi < 10; ++hbi) {
            const int hb = hbi * 8;
            f8 acc = *(const f8*)(&s_biasq[hb]);

            #pragma unroll 1
            for (int d4 = 0; d4 < 16; ++d4) {
                const float4 kd = kr[d4];
                #pragma unroll
                for (int dd = 0; dd < 4; ++dd) {
                    const float kv = (dd == 0) ? kd.x : (dd == 1) ? kd.y
                                   : (dd == 2) ? kd.z : kd.w;
                    f8 w = *(const f8*)(&s_weff[d4 * 4 + dd][hb]);
                    #pragma unroll
                    for (int j = 0; j < 8; ++j) acc[j] = fmaf(kv, w[j], acc[j]);
                }
            }

            // PReLU + layer-2 accumulation (broadcast LDS reads)
            f8 al = *(const f8*)(&s_a0[hb]);
            #pragma unroll
            for (int j = 0; j < 8; ++j) {
                const float x = acc[j];
                const float h0v = (x >= 0.0f) ? x : al[j] * x;
                const float* w1r = &s_W1[hb + j][0];
                #pragma unroll
                for (int g8 = 0; g8 < 5; ++g8) {
                    f8 w = *(const f8*)(w1r + g8 * 8);
                    #pragma unroll
                    for (int u = 0; u < 8; ++u)
                        h1acc[g8 * 8 + u] = fmaf(h0v, w[u], h1acc[g8 * 8 + u]);
                }
            }
        }

        float lg = bo[0];
        #pragma unroll
        for (int g8 = 0; g8 < 5; ++g8) {
            f8 bb = *(const f8*)(&s_b1[g8 * 8]);
            f8 aa = *(const f8*)(&s_a1[g8 * 8]);
            f8 ww = *(const f8*)(&s_Wo[g8 * 8]);
            #pragma unroll
            for (int u = 0; u < 8; ++u) {
                const float x = h1acc[g8 * 8 + u] + bb[u];
                const float hv = (x >= 0.0f) ? x : aa[u] * x;
                lg = fmaf(hv, ww[u], lg);
            }
        }
        logit = (mask[(size_t)b * T + tid] == 0) ? NEG_INF_V : lg;
    } else {
        logit = -INFINITY;   // pads: exp() = 0 even in all-masked rows
    }

    // ---- Softmax: wave shuffle reduce + tiny LDS combine ----
    float m = logit;
    #pragma unroll
    for (int off = 32; off > 0; off >>= 1) m = fmaxf(m, __shfl_xor(m, off));
    if ((tid & 63) == 0) s_red[tid >> 6] = m;
    __syncthreads();
    m = fmaxf(fmaxf(s_red[0], s_red[1]), fmaxf(s_red[2], s_red[3]));
    const float e = expf(logit - m);
    s_w[tid] = e;
    float ssum = e;
    #pragma unroll
    for (int off = 32; off > 0; off >>= 1) ssum += __shfl_xor(ssum, off);
    if ((tid & 63) == 0) s_red[4 + (tid >> 6)] = ssum;
    __syncthreads();
    const float inv = 1.0f / (s_red[4] + s_red[5] + s_red[6] + s_red[7]);

    // ---- Phase C: out[b,d] = sum_t w_t * v[b,t,d] (coalesced in d) ----
    const int d = tid & (D - 1);
    const int c = tid >> 6;
    constexpr int TC = T / 4;          // 50
    float acc2 = 0.0f;
    const float* vp = v + ((size_t)b * T + c * TC) * D + d;
    #pragma unroll 4
    for (int t = 0; t < TC; ++t)
        acc2 = fmaf(s_w[c * TC + t], vp[t * D], acc2);
    s_part[c][d] = acc2;
    __syncthreads();
    if (tid < D) {
        out[(size_t)b * D + tid] =
            (s_part[0][tid] + s_part[1][tid] + s_part[2][tid] + s_part[3][tid]) * inv;
    }
}

extern "C" void kernel_launch(void* const* d_in, const int* in_sizes, int n_in,
                              void* d_out, int out_size, void* d_ws, size_t ws_size,
                              hipStream_t stream) {
    const float* q  = (const float*)d_in[0];
    const float* k  = (const float*)d_in[1];
    const float* v  = (const float*)d_in[2];
    const float* W0 = (const float*)d_in[3];
    const float* b0 = (const float*)d_in[4];
    const float* a0 = (const float*)d_in[5];
    const float* W1 = (const float*)d_in[6];
    const float* b1 = (const float*)d_in[7];
    const float* a1 = (const float*)d_in[8];
    const float* Wo = (const float*)d_in[9];
    const float* bo = (const float*)d_in[10];
    const int*  mask = (const int*)d_in[11];
    float* out = (float*)d_out;

    const int B = in_sizes[0] / D;     // 2048
    attn_fused<<<dim3(B), dim3(BLOCK), 0, stream>>>(
        q, k, v, W0, b0, a0, W1, b1, a1, Wo, bo, mask, out);
}

// Round 4
// 473.544 us; speedup vs baseline: 1.1179x; 1.1179x over previous
//
#include <hip/hip_runtime.h>
#include <math.h>

constexpr int D  = 64;
constexpr int T  = 200;
constexpr int H0 = 80;
constexpr int H1 = 40;
constexpr int BLOCK = 256;
constexpr float NEG_INF_V = -4294967295.0f;

typedef float f8 __attribute__((ext_vector_type(8)));

// __launch_bounds__(256, 4): 4 waves/EU min -> 128-VGPR cap. This is the whole
// point of this revision: kr[16] (64 VGPRs) + h1acc[40] + acc[8] ~= 127 live
// fits, so the allocator keeps the k row in registers instead of re-loading it
// from global on every hbi iteration (R3: VGPR=68, k re-fetched 10x, FETCH 540MB).
__global__ __launch_bounds__(BLOCK, 4) void attn_fused(
    const float* __restrict__ q, const float* __restrict__ k,
    const float* __restrict__ v, const float* __restrict__ W0,
    const float* __restrict__ b0, const float* __restrict__ a0,
    const float* __restrict__ W1, const float* __restrict__ b1,
    const float* __restrict__ a1, const float* __restrict__ Wo,
    const float* __restrict__ bo, const int* __restrict__ mask,
    float* __restrict__ out)
{
    __shared__ float s_q[D];
    __shared__ __align__(16) float s_weff[D][H0];   // 20 KB folded layer-1
    __shared__ __align__(16) float s_W1[H0][H1];    // 12.8 KB
    __shared__ __align__(16) float s_biasq[H0];
    __shared__ __align__(16) float s_a0[H0];
    __shared__ __align__(16) float s_b1[H1];
    __shared__ __align__(16) float s_a1[H1];
    __shared__ __align__(16) float s_Wo[H1];
    __shared__ float s_w[BLOCK];
    __shared__ float s_red[8];
    __shared__ float s_part[4][D];

    const int tid = threadIdx.x;
    const int b   = blockIdx.x;

    // ---- Phase A: stage weights, fold layer-1 per batch ----
    if (tid < D) s_q[tid] = q[(size_t)b * D + tid];
    for (int i = tid; i < H0 * H1; i += BLOCK) ((float*)s_W1)[i] = W1[i];
    if (tid < H1) { s_b1[tid] = b1[tid]; s_a1[tid] = a1[tid]; s_Wo[tid] = Wo[tid]; }
    if (tid < H0) s_a0[tid] = a0[tid];
    __syncthreads();

    for (int i = tid; i < D * H0; i += BLOCK) {
        int d = i / H0;
        ((float*)s_weff)[i] = W0[64 * H0 + i] - W0[128 * H0 + i]
                            + s_q[d] * W0[192 * H0 + i];
    }
    if (tid < H0) {
        float acc = b0[tid];
        #pragma unroll 4
        for (int d = 0; d < D; ++d)
            acc = fmaf(s_q[d], W0[d * H0 + tid] + W0[(128 + d) * H0 + tid], acc);
        s_biasq[tid] = acc;
    }

    const int mval = (tid < T) ? mask[(size_t)b * T + tid] : 0;
    __syncthreads();

    // ---- Phase B: thread t = tid computes the MLP logit ----
    float logit;
    if (tid < T) {
        const float4* kp4 = (const float4*)(k + ((size_t)b * T + tid) * D);
        float4 kr[16];
        #pragma unroll
        for (int i = 0; i < 16; ++i) kr[i] = kp4[i];

        float h1acc[H1];
        #pragma unroll
        for (int g = 0; g < H1; ++g) h1acc[g] = 0.0f;

        #pragma unroll 1
        for (int hbi = 0; hbi < 10; ++hbi) {
            const int hb = hbi * 8;
            f8 acc = *(const f8*)(&s_biasq[hb]);

            #pragma unroll 1
            for (int d4 = 0; d4 < 16; ++d4) {
                const float4 kd = kr[d4];
                #pragma unroll
                for (int dd = 0; dd < 4; ++dd) {
                    const float kv = (dd == 0) ? kd.x : (dd == 1) ? kd.y
                                   : (dd == 2) ? kd.z : kd.w;
                    f8 w = *(const f8*)(&s_weff[d4 * 4 + dd][hb]);
                    #pragma unroll
                    for (int j = 0; j < 8; ++j) acc[j] = fmaf(kv, w[j], acc[j]);
                }
            }

            // PReLU + layer-2 accumulation (broadcast LDS reads)
            f8 al = *(const f8*)(&s_a0[hb]);
            #pragma unroll
            for (int j = 0; j < 8; ++j) {
                const float x = acc[j];
                const float h0v = (x >= 0.0f) ? x : al[j] * x;
                const float* w1r = &s_W1[hb + j][0];
                #pragma unroll
                for (int g8 = 0; g8 < 5; ++g8) {
                    f8 w = *(const f8*)(w1r + g8 * 8);
                    #pragma unroll
                    for (int u = 0; u < 8; ++u)
                        h1acc[g8 * 8 + u] = fmaf(h0v, w[u], h1acc[g8 * 8 + u]);
                }
            }
        }

        float lg = bo[0];
        #pragma unroll
        for (int g8 = 0; g8 < 5; ++g8) {
            f8 bb = *(const f8*)(&s_b1[g8 * 8]);
            f8 aa = *(const f8*)(&s_a1[g8 * 8]);
            f8 ww = *(const f8*)(&s_Wo[g8 * 8]);
            #pragma unroll
            for (int u = 0; u < 8; ++u) {
                const float x = h1acc[g8 * 8 + u] + bb[u];
                const float hv = (x >= 0.0f) ? x : aa[u] * x;
                lg = fmaf(hv, ww[u], lg);
            }
        }
        logit = (mval == 0) ? NEG_INF_V : lg;
    } else {
        logit = -INFINITY;   // pads: exp() = 0 even in all-masked rows
    }

    // ---- Softmax: wave shuffle reduce + tiny LDS combine ----
    float m = logit;
    #pragma unroll
    for (int off = 32; off > 0; off >>= 1) m = fmaxf(m, __shfl_xor(m, off));
    if ((tid & 63) == 0) s_red[tid >> 6] = m;
    __syncthreads();
    m = fmaxf(fmaxf(s_red[0], s_red[1]), fmaxf(s_red[2], s_red[3]));
    const float e = expf(logit - m);
    s_w[tid] = e;
    float ssum = e;
    #pragma unroll
    for (int off = 32; off > 0; off >>= 1) ssum += __shfl_xor(ssum, off);
    if ((tid & 63) == 0) s_red[4 + (tid >> 6)] = ssum;
    __syncthreads();
    const float inv = 1.0f / (s_red[4] + s_red[5] + s_red[6] + s_red[7]);

    // ---- Phase C: out[b,d] = sum_t w_t * v[b,t,d] (coalesced in d) ----
    const int d = tid & (D - 1);
    const int c = tid >> 6;
    constexpr int TC = T / 4;          // 50
    float acc2 = 0.0f;
    const float* vp = v + ((size_t)b * T + c * TC) * D + d;
    #pragma unroll 4
    for (int t = 0; t < TC; ++t)
        acc2 = fmaf(s_w[c * TC + t], vp[t * D], acc2);
    s_part[c][d] = acc2;
    __syncthreads();
    if (tid < D) {
        out[(size_t)b * D + tid] =
            (s_part[0][tid] + s_part[1][tid] + s_part[2][tid] + s_part[3][tid]) * inv;
    }
}

extern "C" void kernel_launch(void* const* d_in, const int* in_sizes, int n_in,
                              void* d_out, int out_size, void* d_ws, size_t ws_size,
                              hipStream_t stream) {
    const float* q  = (const float*)d_in[0];
    const float* k  = (const float*)d_in[1];
    const float* v  = (const float*)d_in[2];
    const float* W0 = (const float*)d_in[3];
    const float* b0 = (const float*)d_in[4];
    const float* a0 = (const float*)d_in[5];
    const float* W1 = (const float*)d_in[6];
    const float* b1 = (const float*)d_in[7];
    const float* a1 = (const float*)d_in[8];
    const float* Wo = (const float*)d_in[9];
    const float* bo = (const float*)d_in[10];
    const int*  mask = (const int*)d_in[11];
    float* out = (float*)d_out;

    const int B = in_sizes[0] / D;     // 2048
    attn_fused<<<dim3(B), dim3(BLOCK), 0, stream>>>(
        q, k, v, W0, b0, a0, W1, b1, a1, Wo, bo, mask, out);
}